// Round 2
// baseline (378.293 us; speedup 1.0000x reference)
//
#include <hip/hip_runtime.h>
#include <hip/hip_bf16.h>

// Problem constants
#define BB 64
#define CC 3
#define HH 512
#define WW 512
#define PP 16
#define IN_F 256
#define HD 512
#define PATCH_DIM 768   // 16*16*3
#define NPATCH 1024     // 32*32

// ---------------------------------------------------------------------------
// Math collapse: softmax over a size-1 axis == 1, so attn is all-ones and
//   out[b,h,d] = sum_n feat_h[b,h,n,d]
// Linearity lets the patch-sum move to the front:
//   S[b,k]   = sum_{h,w} feature[b, c, 16h+p1, 16w+p2],  k=(p1*16+p2)*3+c
//   t1       = S @ W_patch + 1024*b_patch         (768 -> 256)
//   o        = t1 @ W                             (256 -> 512)
//   z        = o @ W_out                          (512 -> 256)
//   x        = 0.25*(z + b_out) + 0.75*token
//   out      = LayerNorm(x)*gamma + beta
// ---------------------------------------------------------------------------

// Kernel 1: S[b, (p1*16+p2)*3 + c] = sum_{h,w} feature[b, c, 16h+p1, 16w+p2]
// grid = B*C*16 blocks, 256 threads. Each block handles one (b, c, p1) slice:
// 32 rows (y = p1 + 16h) of 512 fp32 = 2 KB each, read as float4 (16 B/lane).
__global__ __launch_bounds__(256)
void patch_reduce_kernel(const float* __restrict__ feature,
                         float* __restrict__ S)
{
    int bid = blockIdx.x;
    int p1 = bid & 15;
    int tmp = bid >> 4;
    int c = tmp % 3;
    int b = tmp / 3;
    int t = threadIdx.x;

    const size_t base_bc = (size_t)(b * 3 + c) * (size_t)(HH * WW);

    // chunk u = idx & 127 (128 float4 per row); x = 4u + e, e in [0,4)
    // p2 = x & 15 = 4*(u&3) + e, and u&3 == t&3 (256 % 4 == 0)
    // -> each thread owns 4 fixed p2 bins: pb..pb+3, pb = 4*(t&3)
    float acc[4] = {0.f, 0.f, 0.f, 0.f};

#pragma unroll
    for (int i = 0; i < 16; ++i) {
        int idx = i * 256 + t;        // 0..4095
        int h = idx >> 7;             // 0..31
        int u = idx & 127;            // float4-chunk within row
        size_t off = base_bc + (size_t)(p1 + 16 * h) * WW + (size_t)u * 4;
        float4 v = *(const float4*)(feature + off);
        acc[0] += v.x;
        acc[1] += v.y;
        acc[2] += v.z;
        acc[3] += v.w;
    }

    // Reduce 256 threads * 4 accs -> 16 bins (p2 = 0..15)
    __shared__ float red[16 * 68];   // [bin][64 contributors], stride 68 pads banks
    __shared__ float red2[16 * 8];
    int g = t >> 2;                  // 0..63
    int pb = (t & 3) * 4;
#pragma unroll
    for (int j = 0; j < 4; ++j)
        red[(pb + j) * 68 + g] = acc[j];
    __syncthreads();

    if (t < 128) {
        int bin = t >> 3;
        int l = t & 7;
        float s = 0.f;
#pragma unroll
        for (int q = 0; q < 8; ++q)
            s += red[bin * 68 + l + 8 * q];
        red2[bin * 8 + l] = s;
    }
    __syncthreads();

    if (t < 16) {
        float s = 0.f;
#pragma unroll
        for (int l = 0; l < 8; ++l)
            s += red2[t * 8 + l];
        // k = (p1*16 + p2)*3 + c
        S[(size_t)b * PATCH_DIM + (size_t)(p1 * 16 + t) * 3 + c] = s;
    }
}

// Kernel 2: per-batch fused chain (see collapse above).
// grid = 64 blocks (one per batch), 256 threads.
__global__ __launch_bounds__(256)
void fuse_kernel(const float* __restrict__ S,
                 const float* __restrict__ Wp,
                 const float* __restrict__ bp,
                 const float* __restrict__ Wm,
                 const float* __restrict__ Wo,
                 const float* __restrict__ bo,
                 const float* __restrict__ tok,
                 const float* __restrict__ gamma,
                 const float* __restrict__ beta,
                 float* __restrict__ out)
{
    int b = blockIdx.x;
    int t = threadIdx.x;

    __shared__ float sS[PATCH_DIM];
    __shared__ float sT[IN_F];
    __shared__ float sO[HD];
    __shared__ float wred[8];
    __shared__ float stats[2];

    for (int k = t; k < PATCH_DIM; k += 256)
        sS[k] = S[(size_t)b * PATCH_DIM + k];
    __syncthreads();

    // t1[t] = sum_k S[k] * Wp[k][t] + 1024*bp[t]
    float acc = 0.f;
#pragma unroll 8
    for (int k = 0; k < PATCH_DIM; ++k)
        acc += sS[k] * Wp[k * IN_F + t];
    acc += 1024.f * bp[t];
    sT[t] = acc;
    __syncthreads();

    // o[t], o[t+256] = sum_i t1[i] * Wm[i][...]
    float o0 = 0.f, o1 = 0.f;
#pragma unroll 8
    for (int i = 0; i < IN_F; ++i) {
        float ti = sT[i];
        o0 += ti * Wm[i * HD + t];
        o1 += ti * Wm[i * HD + t + 256];
    }
    sO[t] = o0;
    sO[t + 256] = o1;
    __syncthreads();

    // z[t] = sum_j o[j] * Wo[j][t]
    float z = 0.f;
#pragma unroll 8
    for (int j = 0; j < HD; ++j)
        z += sO[j] * Wo[j * IN_F + t];

    float x = 0.25f * (z + bo[t]) + 0.75f * tok[b * IN_F + t];

    // LayerNorm over 256 elems: wave64 shuffle reduce + cross-wave via LDS
    float s1 = x, s2 = x * x;
#pragma unroll
    for (int off = 32; off > 0; off >>= 1) {
        s1 += __shfl_down(s1, off);
        s2 += __shfl_down(s2, off);
    }
    int wave = t >> 6;
    if ((t & 63) == 0) {
        wred[wave * 2]     = s1;
        wred[wave * 2 + 1] = s2;
    }
    __syncthreads();
    if (t == 0) {
        float a1 = wred[0] + wred[2] + wred[4] + wred[6];
        float a2 = wred[1] + wred[3] + wred[5] + wred[7];
        float mu = a1 * (1.f / 256.f);
        float var = a2 * (1.f / 256.f) - mu * mu;
        stats[0] = mu;
        stats[1] = rsqrtf(var + 1e-5f);
    }
    __syncthreads();

    float y = (x - stats[0]) * stats[1] * gamma[t] + beta[t];
    out[b * IN_F + t] = y;
}

extern "C" void kernel_launch(void* const* d_in, const int* in_sizes, int n_in,
                              void* d_out, int out_size, void* d_ws, size_t ws_size,
                              hipStream_t stream)
{
    const float* token   = (const float*)d_in[0];
    const float* feature = (const float*)d_in[1];
    const float* W_patch = (const float*)d_in[2];
    const float* b_patch = (const float*)d_in[3];
    const float* W       = (const float*)d_in[4];
    // d_in[5] = a_self, d_in[6] = a_neigh : dead (softmax over size-1 axis == 1)
    const float* W_out   = (const float*)d_in[7];
    const float* b_out   = (const float*)d_in[8];
    const float* gamma   = (const float*)d_in[9];
    const float* beta    = (const float*)d_in[10];

    float* out = (float*)d_out;
    float* S = (float*)d_ws;   // 64*768 floats = 196608 B

    dim3 grid1(BB * CC * 16);
    patch_reduce_kernel<<<grid1, 256, 0, stream>>>(feature, S);

    fuse_kernel<<<BB, 256, 0, stream>>>(S, W_patch, b_patch, W, W_out, b_out,
                                        token, gamma, beta, out);
}

// Round 3
// 338.013 us; speedup vs baseline: 1.1192x; 1.1192x over previous
//
#include <hip/hip_runtime.h>
#include <hip/hip_bf16.h>

// Problem constants
#define BB 64
#define CC 3
#define HH 512
#define WW 512
#define PP 16
#define IN_F 256
#define HD 512
#define PATCH_DIM 768   // 16*16*3
#define NPATCH 1024     // 32*32

// ---------------------------------------------------------------------------
// Math collapse: softmax over a size-1 axis == 1, so attn is all-ones and
//   out[b,h,d] = sum_n feat_h[b,h,n,d]
// Linearity lets the patch-sum move to the front:
//   S[b,k]   = sum_{h,w} feature[b, c, 16h+p1, 16w+p2],  k=(p1*16+p2)*3+c
//   t1       = S @ W_patch + 1024*b_patch         (768 -> 256)
//   o        = t1 @ W                             (256 -> 512)
//   z        = o @ W_out                          (512 -> 256)
//   x        = 0.25*(z + b_out) + 0.75*token
//   out      = LayerNorm(x)*gamma + beta
// ---------------------------------------------------------------------------

// Kernel 1: S[b, (p1*16+p2)*3 + c] = sum_{h,w} feature[b, c, 16h+p1, 16w+p2]
// grid = B*C*16 blocks, 256 threads. Each block handles one (b, c, p1) slice:
// 32 rows (y = p1 + 16h) of 512 fp32 = 2 KB each, read as float4 (16 B/lane).
__global__ __launch_bounds__(256)
void patch_reduce_kernel(const float* __restrict__ feature,
                         float* __restrict__ S)
{
    int bid = blockIdx.x;
    int p1 = bid & 15;
    int tmp = bid >> 4;
    int c = tmp % 3;
    int b = tmp / 3;
    int t = threadIdx.x;

    const size_t base_bc = (size_t)(b * 3 + c) * (size_t)(HH * WW);

    // chunk u = idx & 127 (128 float4 per row); x = 4u + e, e in [0,4)
    // p2 = x & 15 = 4*(u&3) + e, and u&3 == t&3 (256 % 4 == 0)
    // -> each thread owns 4 fixed p2 bins: pb..pb+3, pb = 4*(t&3)
    float acc[4] = {0.f, 0.f, 0.f, 0.f};

#pragma unroll
    for (int i = 0; i < 16; ++i) {
        int idx = i * 256 + t;        // 0..4095
        int h = idx >> 7;             // 0..31
        int u = idx & 127;            // float4-chunk within row
        size_t off = base_bc + (size_t)(p1 + 16 * h) * WW + (size_t)u * 4;
        float4 v = *(const float4*)(feature + off);
        acc[0] += v.x;
        acc[1] += v.y;
        acc[2] += v.z;
        acc[3] += v.w;
    }

    // Reduce 256 threads * 4 accs -> 16 bins (p2 = 0..15)
    __shared__ float red[16 * 68];   // [bin][64 contributors], stride 68 pads banks
    __shared__ float red2[16 * 8];
    int g = t >> 2;                  // 0..63
    int pb = (t & 3) * 4;
#pragma unroll
    for (int j = 0; j < 4; ++j)
        red[(pb + j) * 68 + g] = acc[j];
    __syncthreads();

    if (t < 128) {
        int bin = t >> 3;
        int l = t & 7;
        float s = 0.f;
#pragma unroll
        for (int q = 0; q < 8; ++q)
            s += red[bin * 68 + l + 8 * q];
        red2[bin * 8 + l] = s;
    }
    __syncthreads();

    if (t < 16) {
        float s = 0.f;
#pragma unroll
        for (int l = 0; l < 8; ++l)
            s += red2[t * 8 + l];
        // k = (p1*16 + p2)*3 + c
        S[(size_t)b * PATCH_DIM + (size_t)(p1 * 16 + t) * 3 + c] = s;
    }
}

// Kernel 2: per-batch fused chain (see collapse above).
// grid = 64 blocks (one per batch), 256 threads.
// v2: 4 independent accumulators per GEMM stage -> serial FMA chain /4,
//     4+ independent global loads in flight per group for L2-latency hiding.
__global__ __launch_bounds__(256)
void fuse_kernel(const float* __restrict__ S,
                 const float* __restrict__ Wp,
                 const float* __restrict__ bp,
                 const float* __restrict__ Wm,
                 const float* __restrict__ Wo,
                 const float* __restrict__ bo,
                 const float* __restrict__ tok,
                 const float* __restrict__ gamma,
                 const float* __restrict__ beta,
                 float* __restrict__ out)
{
    int b = blockIdx.x;
    int t = threadIdx.x;

    __shared__ float sS[PATCH_DIM];
    __shared__ float sT[IN_F];
    __shared__ float sO[HD];
    __shared__ float wred[8];
    __shared__ float stats[2];

    // prefetch the small per-output operands early (independent of the chain)
    float bo_t    = bo[t];
    float tok_t   = tok[b * IN_F + t];
    float gamma_t = gamma[t];
    float beta_t  = beta[t];
    float bp_t    = bp[t];

    for (int k = t; k < PATCH_DIM; k += 256)
        sS[k] = S[(size_t)b * PATCH_DIM + k];
    __syncthreads();

    // t1[t] = sum_k S[k] * Wp[k][t] + 1024*bp[t]   (768 iters, 4 accs)
    {
        float a0 = 0.f, a1 = 0.f, a2 = 0.f, a3 = 0.f;
#pragma unroll 4
        for (int k = 0; k < PATCH_DIM; k += 4) {
            a0 += sS[k + 0] * Wp[(k + 0) * IN_F + t];
            a1 += sS[k + 1] * Wp[(k + 1) * IN_F + t];
            a2 += sS[k + 2] * Wp[(k + 2) * IN_F + t];
            a3 += sS[k + 3] * Wp[(k + 3) * IN_F + t];
        }
        sT[t] = (a0 + a1) + (a2 + a3) + 1024.f * bp_t;
    }
    __syncthreads();

    // o[t], o[t+256] = sum_i t1[i] * Wm[i][...]   (256 iters, 4 accs each)
    {
        float a00 = 0.f, a01 = 0.f, a02 = 0.f, a03 = 0.f;
        float a10 = 0.f, a11 = 0.f, a12 = 0.f, a13 = 0.f;
#pragma unroll 4
        for (int i = 0; i < IN_F; i += 4) {
            float t0 = sT[i + 0], t1v = sT[i + 1], t2 = sT[i + 2], t3 = sT[i + 3];
            a00 += t0  * Wm[(i + 0) * HD + t];
            a01 += t1v * Wm[(i + 1) * HD + t];
            a02 += t2  * Wm[(i + 2) * HD + t];
            a03 += t3  * Wm[(i + 3) * HD + t];
            a10 += t0  * Wm[(i + 0) * HD + t + 256];
            a11 += t1v * Wm[(i + 1) * HD + t + 256];
            a12 += t2  * Wm[(i + 2) * HD + t + 256];
            a13 += t3  * Wm[(i + 3) * HD + t + 256];
        }
        sO[t]       = (a00 + a01) + (a02 + a03);
        sO[t + 256] = (a10 + a11) + (a12 + a13);
    }
    __syncthreads();

    // z[t] = sum_j o[j] * Wo[j][t]   (512 iters, 4 accs)
    float z;
    {
        float a0 = 0.f, a1 = 0.f, a2 = 0.f, a3 = 0.f;
#pragma unroll 4
        for (int j = 0; j < HD; j += 4) {
            a0 += sO[j + 0] * Wo[(j + 0) * IN_F + t];
            a1 += sO[j + 1] * Wo[(j + 1) * IN_F + t];
            a2 += sO[j + 2] * Wo[(j + 2) * IN_F + t];
            a3 += sO[j + 3] * Wo[(j + 3) * IN_F + t];
        }
        z = (a0 + a1) + (a2 + a3);
    }

    float x = 0.25f * (z + bo_t) + 0.75f * tok_t;

    // LayerNorm over 256 elems: wave64 shuffle reduce + cross-wave via LDS
    float s1 = x, s2 = x * x;
#pragma unroll
    for (int off = 32; off > 0; off >>= 1) {
        s1 += __shfl_down(s1, off);
        s2 += __shfl_down(s2, off);
    }
    int wave = t >> 6;
    if ((t & 63) == 0) {
        wred[wave * 2]     = s1;
        wred[wave * 2 + 1] = s2;
    }
    __syncthreads();
    if (t == 0) {
        float a1 = wred[0] + wred[2] + wred[4] + wred[6];
        float a2 = wred[1] + wred[3] + wred[5] + wred[7];
        float mu = a1 * (1.f / 256.f);
        float var = a2 * (1.f / 256.f) - mu * mu;
        stats[0] = mu;
        stats[1] = rsqrtf(var + 1e-5f);
    }
    __syncthreads();

    float y = (x - stats[0]) * stats[1] * gamma_t + beta_t;
    out[b * IN_F + t] = y;
}

extern "C" void kernel_launch(void* const* d_in, const int* in_sizes, int n_in,
                              void* d_out, int out_size, void* d_ws, size_t ws_size,
                              hipStream_t stream)
{
    const float* token   = (const float*)d_in[0];
    const float* feature = (const float*)d_in[1];
    const float* W_patch = (const float*)d_in[2];
    const float* b_patch = (const float*)d_in[3];
    const float* W       = (const float*)d_in[4];
    // d_in[5] = a_self, d_in[6] = a_neigh : dead (softmax over size-1 axis == 1)
    const float* W_out   = (const float*)d_in[7];
    const float* b_out   = (const float*)d_in[8];
    const float* gamma   = (const float*)d_in[9];
    const float* beta    = (const float*)d_in[10];

    float* out = (float*)d_out;
    float* S = (float*)d_ws;   // 64*768 floats = 196608 B

    dim3 grid1(BB * CC * 16);
    patch_reduce_kernel<<<grid1, 256, 0, stream>>>(feature, S);

    fuse_kernel<<<BB, 256, 0, stream>>>(S, W_patch, b_patch, W, W_out, b_out,
                                        token, gamma, beta, out);
}

// Round 5
// 308.101 us; speedup vs baseline: 1.2278x; 1.0971x over previous
//
#include <hip/hip_runtime.h>
#include <hip/hip_bf16.h>

// Problem constants
#define BB 64
#define CC 3
#define HH 512
#define WW 512
#define PP 16
#define IN_F 256
#define HD 512
#define PATCH_DIM 768   // 16*16*3
#define NPATCH 1024     // 32*32

// native clang vector for nontemporal builtin (HIP float4 is a struct -> rejected)
typedef float floatx4 __attribute__((ext_vector_type(4)));

// ---------------------------------------------------------------------------
// Math collapse: softmax over a size-1 axis == 1, so attn is all-ones and
//   out[b,h,d] = sum_n feat_h[b,h,n,d]
// Linearity lets the patch-sum move to the front:
//   S[b,k]   = sum_{h,w} feature[b, c, 16h+p1, 16w+p2],  k=(p1*16+p2)*3+c
//   t1       = S @ W_patch + 1024*b_patch         (768 -> 256)
//   o        = t1 @ W                             (256 -> 512)
//   z        = o @ W_out                          (512 -> 256)
//   x        = 0.25*(z + b_out) + 0.75*token
//   out      = LayerNorm(x)*gamma + beta
// ---------------------------------------------------------------------------

// Kernel 1: S[b, (p1*16+p2)*3 + c] = sum_{h,w} feature[b, c, 16h+p1, 16w+p2]
// grid = B*C*16 blocks, 256 threads. Each block handles one (b, c, p1) slice:
// 32 rows (y = p1 + 16h) of 512 fp32 = 2 KB each, read as float4 (16 B/lane),
// nontemporal (read-once stream, keep L2 clean).
__global__ __launch_bounds__(256)
void patch_reduce_kernel(const float* __restrict__ feature,
                         float* __restrict__ S)
{
    int bid = blockIdx.x;
    int p1 = bid & 15;
    int tmp = bid >> 4;
    int c = tmp % 3;
    int b = tmp / 3;
    int t = threadIdx.x;

    const size_t base_bc = (size_t)(b * 3 + c) * (size_t)(HH * WW);

    // chunk u = idx & 127 (128 float4 per row); x = 4u + e, e in [0,4)
    // p2 = x & 15 = 4*(u&3) + e, and u&3 == t&3 (256 % 4 == 0)
    // -> each thread owns 4 fixed p2 bins: pb..pb+3, pb = 4*(t&3)
    float acc[4] = {0.f, 0.f, 0.f, 0.f};

#pragma unroll
    for (int i = 0; i < 16; ++i) {
        int idx = i * 256 + t;        // 0..4095
        int h = idx >> 7;             // 0..31
        int u = idx & 127;            // float4-chunk within row
        size_t off = base_bc + (size_t)(p1 + 16 * h) * WW + (size_t)u * 4;
        floatx4 v = __builtin_nontemporal_load((const floatx4*)(feature + off));
        acc[0] += v.x;
        acc[1] += v.y;
        acc[2] += v.z;
        acc[3] += v.w;
    }

    // Reduce 256 threads * 4 accs -> 16 bins (p2 = 0..15)
    __shared__ float red[16 * 68];   // [bin][64 contributors], stride 68 pads banks
    __shared__ float red2[16 * 8];
    int g = t >> 2;                  // 0..63
    int pb = (t & 3) * 4;
#pragma unroll
    for (int j = 0; j < 4; ++j)
        red[(pb + j) * 68 + g] = acc[j];
    __syncthreads();

    if (t < 128) {
        int bin = t >> 3;
        int l = t & 7;
        float s = 0.f;
#pragma unroll
        for (int q = 0; q < 8; ++q)
            s += red[bin * 68 + l + 8 * q];
        red2[bin * 8 + l] = s;
    }
    __syncthreads();

    if (t < 16) {
        float s = 0.f;
#pragma unroll
        for (int l = 0; l < 8; ++l)
            s += red2[t * 8 + l];
        // k = (p1*16 + p2)*3 + c
        S[(size_t)b * PATCH_DIM + (size_t)(p1 * 16 + t) * 3 + c] = s;
    }
}

// Kernel 2: per-batch fused chain (see collapse above).
// grid = 64 blocks (one per batch), 256 threads.
// v3: each thread computes 4 outputs per stage via float4 weight loads
//     (4x fewer load instructions, same bytes), k-range split across waves
//     (kg) with an LDS cross-wave reduce. 4 indep FMA chains + unroll-8
//     keeps ~8 16B loads in flight -> latency-bound time /4 vs v2.
__global__ __launch_bounds__(256)
void fuse_kernel(const float* __restrict__ S,
                 const float* __restrict__ Wp,
                 const float* __restrict__ bp,
                 const float* __restrict__ Wm,
                 const float* __restrict__ Wo,
                 const float* __restrict__ bo,
                 const float* __restrict__ tok,
                 const float* __restrict__ gamma,
                 const float* __restrict__ beta,
                 float* __restrict__ out)
{
    int b = blockIdx.x;
    int t = threadIdx.x;

    __shared__ float sS[PATCH_DIM];         // 768
    __shared__ float part1[4 * IN_F];       // 1024: stage-1 partials [kg][256]
    __shared__ float sT[IN_F];              // 256
    __shared__ float part2[2 * HD];         // 1024: stage-2 partials [kg][512]
    __shared__ float sO[HD];                // 512
    __shared__ float part3[4 * IN_F];       // 1024: stage-3 partials [kg][256]
    __shared__ float wred[8];
    __shared__ float stats[2];

    // prefetch tiny per-output operands early (independent of the chain)
    float bo_t    = bo[t];
    float tok_t   = tok[b * IN_F + t];
    float gamma_t = gamma[t];
    float beta_t  = beta[t];
    float bp_t    = bp[t];

    for (int k = t; k < PATCH_DIM; k += 256)
        sS[k] = S[(size_t)b * PATCH_DIM + k];
    __syncthreads();

    // ---- Stage 1: t1 = S @ Wp + 1024*bp  (768 -> 256) ----
    // thread (kg = t>>6, j = t&63): outputs 4j..4j+3, k in [kg*192, kg*192+192)
    {
        int j  = t & 63;
        int kg = t >> 6;
        float a0 = 0.f, a1 = 0.f, a2 = 0.f, a3 = 0.f;
        const float* wrow = Wp + (size_t)(kg * 192) * IN_F + 4 * j;
#pragma unroll 8
        for (int i = 0; i < 192; ++i) {
            float s = sS[kg * 192 + i];                  // wave-uniform broadcast
            float4 w = *(const float4*)(wrow + (size_t)i * IN_F);
            a0 += s * w.x; a1 += s * w.y; a2 += s * w.z; a3 += s * w.w;
        }
        part1[kg * IN_F + 4 * j + 0] = a0;
        part1[kg * IN_F + 4 * j + 1] = a1;
        part1[kg * IN_F + 4 * j + 2] = a2;
        part1[kg * IN_F + 4 * j + 3] = a3;
    }
    __syncthreads();
    sT[t] = part1[t] + part1[IN_F + t] + part1[2 * IN_F + t] + part1[3 * IN_F + t]
          + 1024.f * bp_t;
    __syncthreads();

    // ---- Stage 2: o = t1 @ Wm  (256 -> 512) ----
    // thread (kg = t>>7, j = t&127): outputs 4j..4j+3, k in [kg*128, kg*128+128)
    {
        int j  = t & 127;
        int kg = t >> 7;
        float a0 = 0.f, a1 = 0.f, a2 = 0.f, a3 = 0.f;
        const float* wrow = Wm + (size_t)(kg * 128) * HD + 4 * j;
#pragma unroll 8
        for (int i = 0; i < 128; ++i) {
            float s = sT[kg * 128 + i];                  // wave-uniform broadcast
            float4 w = *(const float4*)(wrow + (size_t)i * HD);
            a0 += s * w.x; a1 += s * w.y; a2 += s * w.z; a3 += s * w.w;
        }
        part2[kg * HD + 4 * j + 0] = a0;
        part2[kg * HD + 4 * j + 1] = a1;
        part2[kg * HD + 4 * j + 2] = a2;
        part2[kg * HD + 4 * j + 3] = a3;
    }
    __syncthreads();
    sO[t]       = part2[t]       + part2[HD + t];
    sO[t + 256] = part2[t + 256] + part2[HD + t + 256];
    __syncthreads();

    // ---- Stage 3: z = o @ Wo  (512 -> 256) ----
    // thread (kg = t>>6, j = t&63): outputs 4j..4j+3, k in [kg*128, kg*128+128)
    {
        int j  = t & 63;
        int kg = t >> 6;
        float a0 = 0.f, a1 = 0.f, a2 = 0.f, a3 = 0.f;
        const float* wrow = Wo + (size_t)(kg * 128) * IN_F + 4 * j;
#pragma unroll 8
        for (int i = 0; i < 128; ++i) {
            float s = sO[kg * 128 + i];                  // wave-uniform broadcast
            float4 w = *(const float4*)(wrow + (size_t)i * IN_F);
            a0 += s * w.x; a1 += s * w.y; a2 += s * w.z; a3 += s * w.w;
        }
        part3[kg * IN_F + 4 * j + 0] = a0;
        part3[kg * IN_F + 4 * j + 1] = a1;
        part3[kg * IN_F + 4 * j + 2] = a2;
        part3[kg * IN_F + 4 * j + 3] = a3;
    }
    __syncthreads();
    float z = part3[t] + part3[IN_F + t] + part3[2 * IN_F + t] + part3[3 * IN_F + t];

    float x = 0.25f * (z + bo_t) + 0.75f * tok_t;

    // LayerNorm over 256 elems: wave64 shuffle reduce + cross-wave via LDS
    float s1 = x, s2 = x * x;
#pragma unroll
    for (int off = 32; off > 0; off >>= 1) {
        s1 += __shfl_down(s1, off);
        s2 += __shfl_down(s2, off);
    }
    int wave = t >> 6;
    if ((t & 63) == 0) {
        wred[wave * 2]     = s1;
        wred[wave * 2 + 1] = s2;
    }
    __syncthreads();
    if (t == 0) {
        float a1 = wred[0] + wred[2] + wred[4] + wred[6];
        float a2 = wred[1] + wred[3] + wred[5] + wred[7];
        float mu = a1 * (1.f / 256.f);
        float var = a2 * (1.f / 256.f) - mu * mu;
        stats[0] = mu;
        stats[1] = rsqrtf(var + 1e-5f);
    }
    __syncthreads();

    float y = (x - stats[0]) * stats[1] * gamma_t + beta_t;
    out[b * IN_F + t] = y;
}

extern "C" void kernel_launch(void* const* d_in, const int* in_sizes, int n_in,
                              void* d_out, int out_size, void* d_ws, size_t ws_size,
                              hipStream_t stream)
{
    const float* token   = (const float*)d_in[0];
    const float* feature = (const float*)d_in[1];
    const float* W_patch = (const float*)d_in[2];
    const float* b_patch = (const float*)d_in[3];
    const float* W       = (const float*)d_in[4];
    // d_in[5] = a_self, d_in[6] = a_neigh : dead (softmax over size-1 axis == 1)
    const float* W_out   = (const float*)d_in[7];
    const float* b_out   = (const float*)d_in[8];
    const float* gamma   = (const float*)d_in[9];
    const float* beta    = (const float*)d_in[10];

    float* out = (float*)d_out;
    float* S = (float*)d_ws;   // 64*768 floats = 196608 B

    dim3 grid1(BB * CC * 16);
    patch_reduce_kernel<<<grid1, 256, 0, stream>>>(feature, S);

    fuse_kernel<<<BB, 256, 0, stream>>>(S, W_patch, b_patch, W, W_out, b_out,
                                        token, gamma, beta, out);
}

// Round 7
// 302.269 us; speedup vs baseline: 1.2515x; 1.0193x over previous
//
#include <hip/hip_runtime.h>
#include <hip/hip_bf16.h>

// Problem constants
#define BB 64
#define CC 3
#define HH 512
#define WW 512
#define PP 16
#define IN_F 256
#define HD 512
#define PATCH_DIM 768   // 16*16*3
#define NPATCH 1024     // 32*32

// native clang vector for nontemporal builtin (HIP float4 is a struct -> rejected)
typedef float floatx4 __attribute__((ext_vector_type(4)));

// ---------------------------------------------------------------------------
// Math collapse: softmax over a size-1 axis == 1, so attn is all-ones and
//   out[b,h,d] = sum_n feat_h[b,h,n,d]
// Linearity lets the patch-sum move to the front:
//   S[b,k]   = sum_{h,w} feature[b, c, 16h+p1, 16w+p2],  k=(p1*16+p2)*3+c
//   t1       = S @ W_patch + 1024*b_patch         (768 -> 256)
//   o        = t1 @ W                             (256 -> 512)
//   z        = o @ W_out                          (512 -> 256)
//   x        = 0.25*(z + b_out) + 0.75*token
//   out      = LayerNorm(x)*gamma + beta
// ---------------------------------------------------------------------------

// Kernel 1: S[b, (p1*16+p2)*3 + c] = sum_{h,w} feature[b, c, 16h+p1, 16w+p2]
// grid = B*C*16 blocks, 256 threads. Each block handles one (b, c, p1) slice:
// 32 rows (y = p1 + 16h) of 512 fp32 = 2 KB each, read as float4 (16 B/lane),
// nontemporal (read-once stream, keep L2 clean).
__global__ __launch_bounds__(256)
void patch_reduce_kernel(const float* __restrict__ feature,
                         float* __restrict__ S)
{
    int bid = blockIdx.x;
    int p1 = bid & 15;
    int tmp = bid >> 4;
    int c = tmp % 3;
    int b = tmp / 3;
    int t = threadIdx.x;

    const size_t base_bc = (size_t)(b * 3 + c) * (size_t)(HH * WW);

    // chunk u = idx & 127 (128 float4 per row); x = 4u + e, e in [0,4)
    // p2 = x & 15 = 4*(u&3) + e, and u&3 == t&3 (256 % 4 == 0)
    // -> each thread owns 4 fixed p2 bins: pb..pb+3, pb = 4*(t&3)
    float acc[4] = {0.f, 0.f, 0.f, 0.f};

#pragma unroll
    for (int i = 0; i < 16; ++i) {
        int idx = i * 256 + t;        // 0..4095
        int h = idx >> 7;             // 0..31
        int u = idx & 127;            // float4-chunk within row
        size_t off = base_bc + (size_t)(p1 + 16 * h) * WW + (size_t)u * 4;
        floatx4 v = __builtin_nontemporal_load((const floatx4*)(feature + off));
        acc[0] += v.x;
        acc[1] += v.y;
        acc[2] += v.z;
        acc[3] += v.w;
    }

    // Reduce 256 threads * 4 accs -> 16 bins (p2 = 0..15)
    __shared__ float red[16 * 68];   // [bin][64 contributors], stride 68 pads banks
    __shared__ float red2[16 * 8];
    int g = t >> 2;                  // 0..63
    int pb = (t & 3) * 4;
#pragma unroll
    for (int j = 0; j < 4; ++j)
        red[(pb + j) * 68 + g] = acc[j];
    __syncthreads();

    if (t < 128) {
        int bin = t >> 3;
        int l = t & 7;
        float s = 0.f;
#pragma unroll
        for (int q = 0; q < 8; ++q)
            s += red[bin * 68 + l + 8 * q];
        red2[bin * 8 + l] = s;
    }
    __syncthreads();

    if (t < 16) {
        float s = 0.f;
#pragma unroll
        for (int l = 0; l < 8; ++l)
            s += red2[t * 8 + l];
        // k = (p1*16 + p2)*3 + c
        S[(size_t)b * PATCH_DIM + (size_t)(p1 * 16 + t) * 3 + c] = s;
    }
}

// Kernel 2: per-batch fused chain (see collapse above).
// grid = 64 blocks (one per batch), 512 threads (8 waves -> 2 waves/SIMD).
// v4b: v4 with the epilogue wred race fixed (only waves 0..3 write; waves
//      4..7 carry x=0 and must NOT touch the slots).
__global__ __launch_bounds__(512)
void fuse_kernel(const float* __restrict__ S,
                 const float* __restrict__ Wp,
                 const float* __restrict__ bp,
                 const float* __restrict__ Wm,
                 const float* __restrict__ Wo,
                 const float* __restrict__ bo,
                 const float* __restrict__ tok,
                 const float* __restrict__ gamma,
                 const float* __restrict__ beta,
                 float* __restrict__ out)
{
    int b = blockIdx.x;
    int t = threadIdx.x;

    __shared__ float sS[PATCH_DIM];         // 768
    __shared__ float part1[8 * IN_F];       // 2048: stage-1 partials [kg][256]
    __shared__ float sT[IN_F];              // 256
    __shared__ float part2[4 * HD];         // 2048: stage-2 partials [kg][512]
    __shared__ float sO[HD];                // 512
    __shared__ float part3[8 * IN_F];       // 2048: stage-3 partials [kg][256]
    __shared__ float wred[8];
    __shared__ float stats[2];

    // prefetch tiny per-output operands early (256-wide arrays: guard t<256)
    float bo_t = 0.f, tok_t = 0.f, gamma_t = 0.f, beta_t = 0.f, bp_t = 0.f;
    if (t < IN_F) {
        bo_t    = bo[t];
        tok_t   = tok[b * IN_F + t];
        gamma_t = gamma[t];
        beta_t  = beta[t];
        bp_t    = bp[t];
    }

    for (int k = t; k < PATCH_DIM; k += 512)
        sS[k] = S[(size_t)b * PATCH_DIM + k];
    __syncthreads();

    // ---- Stage 1: t1 = S @ Wp + 1024*bp  (768 -> 256) ----
    // thread (kg = t>>6 in 0..7, j = t&63): outputs 4j..4j+3, k in [kg*96, +96)
    {
        int j  = t & 63;
        int kg = t >> 6;
        float a0 = 0.f, a1 = 0.f, a2 = 0.f, a3 = 0.f;
        const float* wrow = Wp + (size_t)(kg * 96) * IN_F + 4 * j;
#pragma unroll 8
        for (int i = 0; i < 96; ++i) {
            float s = sS[kg * 96 + i];                   // wave-uniform broadcast
            float4 w = *(const float4*)(wrow + (size_t)i * IN_F);
            a0 += s * w.x; a1 += s * w.y; a2 += s * w.z; a3 += s * w.w;
        }
        part1[kg * IN_F + 4 * j + 0] = a0;
        part1[kg * IN_F + 4 * j + 1] = a1;
        part1[kg * IN_F + 4 * j + 2] = a2;
        part1[kg * IN_F + 4 * j + 3] = a3;
    }
    __syncthreads();
    if (t < IN_F) {
        float s = 0.f;
#pragma unroll
        for (int kg = 0; kg < 8; ++kg)
            s += part1[kg * IN_F + t];
        sT[t] = s + 1024.f * bp_t;
    }
    __syncthreads();

    // ---- Stage 2: o = t1 @ Wm  (256 -> 512) ----
    // thread (kg = t>>7 in 0..3, j = t&127): outputs 4j..4j+3, k in [kg*64, +64)
    {
        int j  = t & 127;
        int kg = t >> 7;
        float a0 = 0.f, a1 = 0.f, a2 = 0.f, a3 = 0.f;
        const float* wrow = Wm + (size_t)(kg * 64) * HD + 4 * j;
#pragma unroll 8
        for (int i = 0; i < 64; ++i) {
            float s = sT[kg * 64 + i];                   // wave-uniform broadcast
            float4 w = *(const float4*)(wrow + (size_t)i * HD);
            a0 += s * w.x; a1 += s * w.y; a2 += s * w.z; a3 += s * w.w;
        }
        part2[kg * HD + 4 * j + 0] = a0;
        part2[kg * HD + 4 * j + 1] = a1;
        part2[kg * HD + 4 * j + 2] = a2;
        part2[kg * HD + 4 * j + 3] = a3;
    }
    __syncthreads();
    sO[t] = part2[t] + part2[HD + t] + part2[2 * HD + t] + part2[3 * HD + t];
    __syncthreads();

    // ---- Stage 3: z = o @ Wo  (512 -> 256) ----
    // thread (kg = t>>6 in 0..7, j = t&63): outputs 4j..4j+3, k in [kg*64, +64)
    {
        int j  = t & 63;
        int kg = t >> 6;
        float a0 = 0.f, a1 = 0.f, a2 = 0.f, a3 = 0.f;
        const float* wrow = Wo + (size_t)(kg * 64) * IN_F + 4 * j;
#pragma unroll 8
        for (int i = 0; i < 64; ++i) {
            float s = sO[kg * 64 + i];                   // wave-uniform broadcast
            float4 w = *(const float4*)(wrow + (size_t)i * IN_F);
            a0 += s * w.x; a1 += s * w.y; a2 += s * w.z; a3 += s * w.w;
        }
        part3[kg * IN_F + 4 * j + 0] = a0;
        part3[kg * IN_F + 4 * j + 1] = a1;
        part3[kg * IN_F + 4 * j + 2] = a2;
        part3[kg * IN_F + 4 * j + 3] = a3;
    }
    __syncthreads();

    // ---- Epilogue (threads 0..255): residual + LayerNorm ----
    float x = 0.f;
    if (t < IN_F) {
        float z = 0.f;
#pragma unroll
        for (int kg = 0; kg < 8; ++kg)
            z += part3[kg * IN_F + t];
        x = 0.25f * (z + bo_t) + 0.75f * tok_t;
    }

    // reduce within waves; only waves 0..3 hold real data (t<256)
    float s1 = x, s2 = x * x;     // zero for t>=256
#pragma unroll
    for (int off = 32; off > 0; off >>= 1) {
        s1 += __shfl_down(s1, off);
        s2 += __shfl_down(s2, off);
    }
    int wave = t >> 6;
    if ((t & 63) == 0 && wave < 4) {   // waves 4..7 must NOT write (race in v4)
        wred[wave * 2]     = s1;
        wred[wave * 2 + 1] = s2;
    }
    __syncthreads();
    if (t == 0) {
        float a1 = wred[0] + wred[2] + wred[4] + wred[6];
        float a2 = wred[1] + wred[3] + wred[5] + wred[7];
        float mu = a1 * (1.f / 256.f);
        float var = a2 * (1.f / 256.f) - mu * mu;
        stats[0] = mu;
        stats[1] = rsqrtf(var + 1e-5f);
    }
    __syncthreads();

    if (t < IN_F) {
        float y = (x - stats[0]) * stats[1] * gamma_t + beta_t;
        out[b * IN_F + t] = y;
    }
}

extern "C" void kernel_launch(void* const* d_in, const int* in_sizes, int n_in,
                              void* d_out, int out_size, void* d_ws, size_t ws_size,
                              hipStream_t stream)
{
    const float* token   = (const float*)d_in[0];
    const float* feature = (const float*)d_in[1];
    const float* W_patch = (const float*)d_in[2];
    const float* b_patch = (const float*)d_in[3];
    const float* W       = (const float*)d_in[4];
    // d_in[5] = a_self, d_in[6] = a_neigh : dead (softmax over size-1 axis == 1)
    const float* W_out   = (const float*)d_in[7];
    const float* b_out   = (const float*)d_in[8];
    const float* gamma   = (const float*)d_in[9];
    const float* beta    = (const float*)d_in[10];

    float* out = (float*)d_out;
    float* S = (float*)d_ws;   // 64*768 floats = 196608 B

    dim3 grid1(BB * CC * 16);
    patch_reduce_kernel<<<grid1, 256, 0, stream>>>(feature, S);

    fuse_kernel<<<BB, 512, 0, stream>>>(S, W_patch, b_patch, W, W_out, b_out,
                                        token, gamma, beta, out);
}

// Round 8
// 299.985 us; speedup vs baseline: 1.2610x; 1.0076x over previous
//
#include <hip/hip_runtime.h>
#include <hip/hip_bf16.h>

// Problem constants
#define BB 64
#define CC 3
#define HH 512
#define WW 512
#define PP 16
#define IN_F 256
#define HD 512
#define PATCH_DIM 768   // 16*16*3
#define NPATCH 1024     // 32*32

// native clang vector for nontemporal builtin (HIP float4 is a struct -> rejected)
typedef float floatx4 __attribute__((ext_vector_type(4)));

// ---------------------------------------------------------------------------
// Math collapse: softmax over a size-1 axis == 1, so attn is all-ones and
//   out[b,h,d] = sum_n feat_h[b,h,n,d]
// Linearity lets the patch-sum move to the front, and Wm@Wo pre-associates:
//   S[b,k]   = sum_{h,w} feature[b, c, 16h+p1, 16w+p2],  k=(p1*16+p2)*3+c
//   M2       = W @ W_out                          (256x256, weights-only)
//   t1       = S @ W_patch + 1024*b_patch         (768 -> 256)
//   z        = t1 @ M2                            (256 -> 256)
//   x        = 0.25*(z + b_out) + 0.75*token
//   out      = LayerNorm(x)*gamma + beta
// ---------------------------------------------------------------------------

// Kernel 0: M2 = Wm @ Wo  (256x512 @ 512x256). One block per output row i,
// 512 threads: j4 = (t&63)*4 output cols, kg = t>>6 k-split (64 k each).
__global__ __launch_bounds__(512)
void m2_kernel(const float* __restrict__ Wm,
               const float* __restrict__ Wo,
               float* __restrict__ M2)
{
    int i = blockIdx.x;           // 0..255
    int t = threadIdx.x;

    __shared__ float sA[HD];          // Wm row i (512)
    __shared__ float part[8 * IN_F];  // [kg][256]

    sA[t] = Wm[(size_t)i * HD + t];
    __syncthreads();

    int j4 = (t & 63) * 4;
    int kg = t >> 6;                  // 0..7
    float a0 = 0.f, a1 = 0.f, a2 = 0.f, a3 = 0.f;
    const float* wrow = Wo + (size_t)(kg * 64) * IN_F + j4;
#pragma unroll 8
    for (int k = 0; k < 64; ++k) {
        float s = sA[kg * 64 + k];
        float4 w = *(const float4*)(wrow + (size_t)k * IN_F);
        a0 += s * w.x; a1 += s * w.y; a2 += s * w.z; a3 += s * w.w;
    }
    part[kg * IN_F + j4 + 0] = a0;
    part[kg * IN_F + j4 + 1] = a1;
    part[kg * IN_F + j4 + 2] = a2;
    part[kg * IN_F + j4 + 3] = a3;
    __syncthreads();

    if (t < IN_F) {
        float s = 0.f;
#pragma unroll
        for (int g = 0; g < 8; ++g)
            s += part[g * IN_F + t];
        M2[(size_t)i * IN_F + t] = s;
    }
}

// Kernel 1: S[b, (p1*16+p2)*3 + c] = sum_{h,w} feature[b, c, 16h+p1, 16w+p2]
// grid = B*C*16 blocks, 256 threads; float4 nontemporal streaming reads.
__global__ __launch_bounds__(256)
void patch_reduce_kernel(const float* __restrict__ feature,
                         float* __restrict__ S)
{
    int bid = blockIdx.x;
    int p1 = bid & 15;
    int tmp = bid >> 4;
    int c = tmp % 3;
    int b = tmp / 3;
    int t = threadIdx.x;

    const size_t base_bc = (size_t)(b * 3 + c) * (size_t)(HH * WW);

    float acc[4] = {0.f, 0.f, 0.f, 0.f};

#pragma unroll
    for (int i = 0; i < 16; ++i) {
        int idx = i * 256 + t;        // 0..4095
        int h = idx >> 7;             // 0..31
        int u = idx & 127;            // float4-chunk within row
        size_t off = base_bc + (size_t)(p1 + 16 * h) * WW + (size_t)u * 4;
        floatx4 v = __builtin_nontemporal_load((const floatx4*)(feature + off));
        acc[0] += v.x;
        acc[1] += v.y;
        acc[2] += v.z;
        acc[3] += v.w;
    }

    __shared__ float red[16 * 68];
    __shared__ float red2[16 * 8];
    int g = t >> 2;                  // 0..63
    int pb = (t & 3) * 4;
#pragma unroll
    for (int j = 0; j < 4; ++j)
        red[(pb + j) * 68 + g] = acc[j];
    __syncthreads();

    if (t < 128) {
        int bin = t >> 3;
        int l = t & 7;
        float s = 0.f;
#pragma unroll
        for (int q = 0; q < 8; ++q)
            s += red[bin * 68 + l + 8 * q];
        red2[bin * 8 + l] = s;
    }
    __syncthreads();

    if (t < 16) {
        float s = 0.f;
#pragma unroll
        for (int l = 0; l < 8; ++l)
            s += red2[t * 8 + l];
        S[(size_t)b * PATCH_DIM + (size_t)(p1 * 16 + t) * 3 + c] = s;
    }
}

// Kernel 2: per-batch fused chain, now TWO GEMM stages (Wp then M2).
// grid = 64 blocks, 512 threads (8 waves).
__global__ __launch_bounds__(512)
void fuse_kernel(const float* __restrict__ S,
                 const float* __restrict__ Wp,
                 const float* __restrict__ bp,
                 const float* __restrict__ M2,
                 const float* __restrict__ bo,
                 const float* __restrict__ tok,
                 const float* __restrict__ gamma,
                 const float* __restrict__ beta,
                 float* __restrict__ out)
{
    int b = blockIdx.x;
    int t = threadIdx.x;

    __shared__ float sS[PATCH_DIM];         // 768
    __shared__ float part1[8 * IN_F];       // stage-1 partials [kg][256]
    __shared__ float sT[IN_F];              // 256
    __shared__ float part2[8 * IN_F];       // stage-2 partials [kg][256]
    __shared__ float wred[8];
    __shared__ float stats[2];

    float bo_t = 0.f, tok_t = 0.f, gamma_t = 0.f, beta_t = 0.f, bp_t = 0.f;
    if (t < IN_F) {
        bo_t    = bo[t];
        tok_t   = tok[b * IN_F + t];
        gamma_t = gamma[t];
        beta_t  = beta[t];
        bp_t    = bp[t];
    }

    for (int k = t; k < PATCH_DIM; k += 512)
        sS[k] = S[(size_t)b * PATCH_DIM + k];
    __syncthreads();

    // ---- Stage 1: t1 = S @ Wp + 1024*bp  (768 -> 256) ----
    {
        int j4 = (t & 63) * 4;
        int kg = t >> 6;              // 0..7, k in [kg*96, +96)
        float a0 = 0.f, a1 = 0.f, a2 = 0.f, a3 = 0.f;
        const float* wrow = Wp + (size_t)(kg * 96) * IN_F + j4;
#pragma unroll 8
        for (int i = 0; i < 96; ++i) {
            float s = sS[kg * 96 + i];
            float4 w = *(const float4*)(wrow + (size_t)i * IN_F);
            a0 += s * w.x; a1 += s * w.y; a2 += s * w.z; a3 += s * w.w;
        }
        part1[kg * IN_F + j4 + 0] = a0;
        part1[kg * IN_F + j4 + 1] = a1;
        part1[kg * IN_F + j4 + 2] = a2;
        part1[kg * IN_F + j4 + 3] = a3;
    }
    __syncthreads();
    if (t < IN_F) {
        float s = 0.f;
#pragma unroll
        for (int kg = 0; kg < 8; ++kg)
            s += part1[kg * IN_F + t];
        sT[t] = s + 1024.f * bp_t;
    }
    __syncthreads();

    // ---- Stage 2: z = t1 @ M2  (256 -> 256) ----
    {
        int j4 = (t & 63) * 4;
        int kg = t >> 6;              // 0..7, k in [kg*32, +32)
        float a0 = 0.f, a1 = 0.f, a2 = 0.f, a3 = 0.f;
        const float* wrow = M2 + (size_t)(kg * 32) * IN_F + j4;
#pragma unroll 8
        for (int i = 0; i < 32; ++i) {
            float s = sT[kg * 32 + i];
            float4 w = *(const float4*)(wrow + (size_t)i * IN_F);
            a0 += s * w.x; a1 += s * w.y; a2 += s * w.z; a3 += s * w.w;
        }
        part2[kg * IN_F + j4 + 0] = a0;
        part2[kg * IN_F + j4 + 1] = a1;
        part2[kg * IN_F + j4 + 2] = a2;
        part2[kg * IN_F + j4 + 3] = a3;
    }
    __syncthreads();

    // ---- Epilogue (threads 0..255): residual + LayerNorm ----
    float x = 0.f;
    if (t < IN_F) {
        float z = 0.f;
#pragma unroll
        for (int kg = 0; kg < 8; ++kg)
            z += part2[kg * IN_F + t];
        x = 0.25f * (z + bo_t) + 0.75f * tok_t;
    }

    float s1 = x, s2 = x * x;     // zero for t>=256
#pragma unroll
    for (int off = 32; off > 0; off >>= 1) {
        s1 += __shfl_down(s1, off);
        s2 += __shfl_down(s2, off);
    }
    int wave = t >> 6;
    if ((t & 63) == 0 && wave < 4) {   // only waves 0..3 hold real data
        wred[wave * 2]     = s1;
        wred[wave * 2 + 1] = s2;
    }
    __syncthreads();
    if (t == 0) {
        float a1 = wred[0] + wred[2] + wred[4] + wred[6];
        float a2 = wred[1] + wred[3] + wred[5] + wred[7];
        float mu = a1 * (1.f / 256.f);
        float var = a2 * (1.f / 256.f) - mu * mu;
        stats[0] = mu;
        stats[1] = rsqrtf(var + 1e-5f);
    }
    __syncthreads();

    if (t < IN_F) {
        float y = (x - stats[0]) * stats[1] * gamma_t + beta_t;
        out[b * IN_F + t] = y;
    }
}

extern "C" void kernel_launch(void* const* d_in, const int* in_sizes, int n_in,
                              void* d_out, int out_size, void* d_ws, size_t ws_size,
                              hipStream_t stream)
{
    const float* token   = (const float*)d_in[0];
    const float* feature = (const float*)d_in[1];
    const float* W_patch = (const float*)d_in[2];
    const float* b_patch = (const float*)d_in[3];
    const float* W       = (const float*)d_in[4];
    // d_in[5] = a_self, d_in[6] = a_neigh : dead (softmax over size-1 axis == 1)
    const float* W_out   = (const float*)d_in[7];
    const float* b_out   = (const float*)d_in[8];
    const float* gamma   = (const float*)d_in[9];
    const float* beta    = (const float*)d_in[10];

    float* out = (float*)d_out;
    float* S  = (float*)d_ws;                 // 64*768 floats
    float* M2 = S + (size_t)BB * PATCH_DIM;   // 256*256 floats (313 KB total used)

    // M2 depends only on weights -> issue first (small, highly parallel)
    m2_kernel<<<IN_F, 512, 0, stream>>>(W, W_out, M2);

    dim3 grid1(BB * CC * 16);
    patch_reduce_kernel<<<grid1, 256, 0, stream>>>(feature, S);

    fuse_kernel<<<BB, 512, 0, stream>>>(S, W_patch, b_patch, M2, b_out,
                                        token, gamma, beta, out);
}